// Round 2
// baseline (382.495 us; speedup 1.0000x reference)
//
#include <hip/hip_runtime.h>
#include <stdint.h>
#include <math.h>

typedef unsigned long long u64;
typedef unsigned int u32;

#define NPI   360000
#define B_IMG 8
#define PRE   1000
#define POST  300
#define CAP   4096
#define NMSF  0.7f
#define IMG_W 800.0f
#define IMG_H 800.0f

// ---- workspace layout (bytes) ----
#define HIST_OFF   0          // 8*4096*4 = 131072
#define CNT_OFF    131072     // 8*4
#define ZERO_BYTES 131136     // hist + cnt zeroed each launch
#define THRESH_OFF 131136     // 8*4
#define CAND_OFF   131200     // 8*4096*8 = 262144
#define BOX_OFF    393344     // 8*1000*16 = 128000  (16B aligned)
#define SCORE_OFF  521344     // 8*1000*4  = 32000
#define VALID_OFF  553344     // 8*16*8    = 1024
#define MASK_OFF   554368     // 8*1000*16*8 = 1024000 (ends 1578368)

__device__ __forceinline__ u32 fkey(float f) {
  u32 u = __float_as_uint(f);
  return (u & 0x80000000u) ? ~u : (u | 0x80000000u);  // ascending-order bits
}

// ---- K1: per-image 12-bit histogram of sortable logit keys ----
__global__ void k_hist(const float* __restrict__ logits, u32* __restrict__ hist) {
  __shared__ u32 h[4096];
  const int img  = blockIdx.y;
  const int base = blockIdx.x * 4096;
  for (int i = threadIdx.x; i < 4096; i += 256) h[i] = 0;
  __syncthreads();
  const float* L = logits + (size_t)img * NPI;
#pragma unroll
  for (int k = 0; k < 16; k++) {
    int e = base + k * 256 + threadIdx.x;
    if (e < NPI) {
      u32 key = fkey(L[e]);
      atomicAdd(&h[key >> 20], 1u);
    }
  }
  __syncthreads();
  u32* H = hist + img * 4096;
  for (int i = threadIdx.x; i < 4096; i += 256) {
    u32 c = h[i];
    if (c) atomicAdd(&H[i], c);
  }
}

// ---- K2: find threshold bin (cumulative from top crosses PRE) ----
__global__ void k_select(const u32* __restrict__ hist, int* __restrict__ thresh) {
  const int img = blockIdx.x;
  const u32* H = hist + img * 4096;
  __shared__ u32 part[256];
  u32 s = 0;
#pragma unroll
  for (int b = 0; b < 16; b++) s += H[threadIdx.x * 16 + b];
  part[threadIdx.x] = s;
  __syncthreads();
  if (threadIdx.x == 0) {
    u32 cum = 0;
    int pb = 255;
    for (; pb > 0; pb--) {
      if (cum + part[pb] >= (u32)PRE) break;
      cum += part[pb];
    }
    int bin;
    for (bin = pb * 16 + 15; bin >= pb * 16; bin--) {
      cum += H[bin];
      if (cum >= (u32)PRE) break;
    }
    if (bin < pb * 16) bin = pb * 16;  // safety clamp
    thresh[img] = bin;
  }
}

// ---- K3: compact candidates >= threshold bin; key = fp32 sigmoid ----
__global__ void k_compact(const float* __restrict__ logits, const int* __restrict__ thresh,
                          u32* __restrict__ cnt, u64* __restrict__ cand) {
  const int img  = blockIdx.y;
  const int tb   = thresh[img];
  const int base = blockIdx.x * 4096;
  const float* L = logits + (size_t)img * NPI;
#pragma unroll
  for (int k = 0; k < 16; k++) {
    int e = base + k * 256 + threadIdx.x;
    if (e < NPI) {
      float x = L[e];
      u32 lkey = fkey(x);
      if ((int)(lkey >> 20) >= tb) {
        // fp32 sigmoid with correctly-rounded exp: replicates numpy f32
        // 1/(1+exp(-x)) tie structure (reference orders by sigmoid, ties by idx)
        float ef = (float)exp(-(double)x);
        float s  = 1.0f / (1.0f + ef);
        u32 pos = atomicAdd(&cnt[img], 1u);
        if (pos < CAP)
          cand[img * CAP + pos] = ((u64)fkey(s) << 32) | (u64)(0xFFFFFFFFu - (u32)e);
      }
    }
  }
}

// ---- K4: bitonic sort candidates (desc), decode/clip top-1000 boxes ----
__global__ __launch_bounds__(1024) void k_sortdecode(
    const float* __restrict__ deltas, const float* __restrict__ anchors,
    const u32* __restrict__ cnt, const u64* __restrict__ cand,
    float4* __restrict__ boxes, float* __restrict__ scores, u64* __restrict__ validw) {
  __shared__ u64 keys[CAP];
  const int img = blockIdx.x;
  const int tid = threadIdx.x;
  u32 n = cnt[img];
  if (n > CAP) n = CAP;
  for (int e = tid; e < CAP; e += 1024)
    keys[e] = (e < (int)n) ? cand[img * CAP + e] : 0ull;
  __syncthreads();
  for (int k = 2; k <= CAP; k <<= 1) {
    for (int j = k >> 1; j > 0; j >>= 1) {
#pragma unroll
      for (int rep = 0; rep < CAP / 1024; rep++) {
        int e = tid + rep * 1024;
        int p = e ^ j;
        if (p > e) {
          u64 a = keys[e], b = keys[p];
          bool up = (e & k) == 0;
          if (up ? (a < b) : (a > b)) { keys[e] = b; keys[p] = a; }
        }
      }
      __syncthreads();
    }
  }
  bool valid = false;
  if (tid < PRE) {
    u64 key = keys[tid];
    u32 hi  = (u32)(key >> 32);
    u32 idx = 0xFFFFFFFFu - (u32)(key & 0xFFFFFFFFu);
    float4 bx = make_float4(0.f, 0.f, 0.f, 0.f);
    float  sc = 0.f;
    if (key != 0ull && idx < NPI) {
      u32 su = (hi & 0x80000000u) ? (hi ^ 0x80000000u) : ~hi;
      sc = __uint_as_float(su);
      size_t off = (size_t)img * NPI + idx;
      float4 d = ((const float4*)deltas)[off];
      float4 a = ((const float4*)anchors)[off];
      float aw = a.z - a.x, ah = a.w - a.y;
      float acx = a.x + 0.5f * aw, acy = a.y + 0.5f * ah;
      float cx = d.x * aw + acx, cy = d.y * ah + acy;
      float w = expf(d.z) * aw, h = expf(d.w) * ah;
      float x1 = cx - 0.5f * w, y1 = cy - 0.5f * h;
      float x2 = cx + 0.5f * w, y2 = cy + 0.5f * h;
      x1 = fminf(fmaxf(x1, 0.f), IMG_W);
      y1 = fminf(fmaxf(y1, 0.f), IMG_H);
      x2 = fminf(fmaxf(x2, 0.f), IMG_W);
      y2 = fminf(fmaxf(y2, 0.f), IMG_H);
      valid = ((x2 - x1) >= 1e-3f) && ((y2 - y1) >= 1e-3f);
      bx = make_float4(x1, y1, x2, y2);
    }
    boxes[img * PRE + tid]  = bx;
    scores[img * PRE + tid] = sc;
  }
  u64 bal = __ballot(valid);
  if ((tid & 63) == 0) validw[img * 16 + (tid >> 6)] = bal;
}

// ---- K5: suppression bitmask, bit (i,c)=1 iff c>i && iou>thr ----
__global__ void k_iou(const float4* __restrict__ boxes, u64* __restrict__ mask) {
  __shared__ float4 sb[PRE];
  __shared__ float  sa[PRE];
  const int img = blockIdx.y;
  for (int c = threadIdx.x; c < PRE; c += 256) {
    float4 b = boxes[img * PRE + c];
    sb[c] = b;
    sa[c] = (b.z - b.x) * (b.w - b.y);
  }
  __syncthreads();
  for (int item = threadIdx.x; item < 1024; item += 256) {
    int r = item >> 4, w = item & 15;
    int i = blockIdx.x * 64 + r;
    if (i >= PRE) continue;
    float4 bi = sb[i];
    float  ai = sa[i];
    u64 bits = 0;
    int cbase  = w << 6;
    int kstart = (i + 1 > cbase) ? (i + 1 - cbase) : 0;
    int kend   = (PRE - cbase < 64) ? (PRE - cbase) : 64;
    for (int k = kstart; k < kend; k++) {
      int c = cbase + k;
      float4 bc = sb[c];
      float ltx = fmaxf(bi.x, bc.x), lty = fmaxf(bi.y, bc.y);
      float rbx = fminf(bi.z, bc.z), rby = fminf(bi.w, bc.w);
      float iw = fmaxf(rbx - ltx, 0.f), ih = fmaxf(rby - lty, 0.f);
      float inter = iw * ih;
      float iou = inter / (ai + sa[c] - inter + 1e-9f);
      if (iou > NMSF) bits |= (1ull << k);
    }
    mask[((size_t)img * PRE + i) * 16 + w] = bits;
  }
}

// ---- K6: greedy scan (1 wave/image, distributed bitmask) + output ----
#define LDSROWS 496
#define NMS_T   320
__global__ __launch_bounds__(NMS_T) void k_nms(
    const u64* __restrict__ mask, const u64* __restrict__ validw,
    const float4* __restrict__ boxes, const float* __restrict__ scores,
    float* __restrict__ out) {
  __shared__ u64 smask[LDSROWS * 16];
  __shared__ int skeeplist[POST];
  __shared__ int skept;
  const int img = blockIdx.x;
  const int tid = threadIdx.x;
  const u64* M = mask + (size_t)img * PRE * 16;
  for (int e = tid; e < LDSROWS * 16; e += NMS_T) smask[e] = M[e];
  __syncthreads();
  if (tid < 64) {
    u64 rem;
    if (tid < 16) {
      rem = ~validw[img * 16 + tid];
      if (tid == 15) rem |= 0xFFFFFF0000000000ull;  // rows 1000..1023 invalid
    } else {
      rem = ~0ull;
    }
    int i = 0, kept = 0;
    while (kept < POST) {
      u64 a = ~rem;
      int w = i >> 6;
      if (tid < w) a = 0;
      else if (tid == w) a &= (~0ull << (i & 63));
      u64 bal = __ballot(a != 0ull);
      if (bal == 0ull) break;
      int wsel = __builtin_ctzll(bal);
      int bitl = (a != 0ull) ? __builtin_ctzll(a) : 0;
      int bit  = __shfl(bitl, wsel);
      i = (wsel << 6) + bit;
      if (tid == 0) skeeplist[kept] = i;
      kept++;
      u64 roww = 0;
      if (tid < 16)
        roww = (i < LDSROWS) ? smask[i * 16 + tid] : M[(size_t)i * 16 + tid];
      rem |= roww;
      i++;
    }
    if (tid == 0) skept = kept;
  }
  __syncthreads();
  if (tid < POST) {   // NMS_T=320 >= POST=300: every row gets written
    float4 bx = make_float4(0.f, 0.f, 0.f, 0.f);
    float  sc = 0.f;
    if (tid < skept) {
      int i = skeeplist[tid];
      bx = boxes[img * PRE + i];
      sc = scores[img * PRE + i];
    }
    float* o = out + ((size_t)img * POST + tid) * 5;
    o[0] = bx.x; o[1] = bx.y; o[2] = bx.z; o[3] = bx.w; o[4] = sc;
  }
}

extern "C" void kernel_launch(void* const* d_in, const int* in_sizes, int n_in,
                              void* d_out, int out_size, void* d_ws, size_t ws_size,
                              hipStream_t stream) {
  const float* logits  = (const float*)d_in[0];
  const float* deltas  = (const float*)d_in[1];
  const float* anchors = (const float*)d_in[2];
  float* out = (float*)d_out;
  char* ws = (char*)d_ws;

  u32* hist     = (u32*)(ws + HIST_OFF);
  u32* cnt      = (u32*)(ws + CNT_OFF);
  int* thresh   = (int*)(ws + THRESH_OFF);
  u64* cand     = (u64*)(ws + CAND_OFF);
  float4* boxes = (float4*)(ws + BOX_OFF);
  float* scores = (float*)(ws + SCORE_OFF);
  u64* validw   = (u64*)(ws + VALID_OFF);
  u64* mask     = (u64*)(ws + MASK_OFF);

  hipMemsetAsync(ws, 0, ZERO_BYTES, stream);
  dim3 g1(88, B_IMG);
  k_hist<<<g1, 256, 0, stream>>>(logits, hist);
  k_select<<<B_IMG, 256, 0, stream>>>(hist, thresh);
  k_compact<<<g1, 256, 0, stream>>>(logits, thresh, cnt, cand);
  k_sortdecode<<<B_IMG, 1024, 0, stream>>>(deltas, anchors, cnt, cand, boxes, scores, validw);
  dim3 g2(16, B_IMG);
  k_iou<<<g2, 256, 0, stream>>>(boxes, mask);
  k_nms<<<B_IMG, NMS_T, 0, stream>>>(mask, validw, boxes, scores, out);
}

// Round 3
// 289.799 us; speedup vs baseline: 1.3199x; 1.3199x over previous
//
#include <hip/hip_runtime.h>
#include <stdint.h>
#include <math.h>

typedef unsigned long long u64;
typedef unsigned int u32;
typedef unsigned short u16;

#define NPI   360000
#define B_IMG 8
#define PRE   1000
#define POST  300
#define CAP   4096
#define NMSF  0.7f
#define IMG_W 800.0f
#define IMG_H 800.0f

#define NBIN  8192            // 13-bit sortable-key histogram
#define CHUNK 12              // blocks per image for hist/compact
#define EPB   (NPI / CHUNK)   // 30000 elements per block
#define F4PB  (EPB / 4)       // 7500 float4 per block
#define LBUF  2048            // per-block candidate buffer

// ---- workspace layout (bytes) ----
#define CNT_OFF    0          // 8*4 = 32
#define VALID_OFF  128        // 8*16*8 = 1024
#define ZERO_BYTES 2048       // cnt + validw zeroed each launch
#define THRESH_OFF 2048       // 8*4
#define RHIST_OFF  4096       // 8*8192*4 = 262144        -> ends 266240
#define BHIST_OFF  266240     // 8*12*8192*2 = 1572864    -> ends 1839104
#define CAND_OFF   1839104    // 8*4096*8 = 262144        -> ends 2101248
#define BOX_OFF    2101248    // 8*1000*16 = 128000       -> ends 2229248
#define SCORE_OFF  2229248    // 8*1000*4 = 32000         -> ends 2261248
#define MASK_OFF   2261248    // 8*1000*16*8 = 1024000    -> ends 3285248

__device__ __forceinline__ u32 fkey(float f) {
  u32 u = __float_as_uint(f);
  return (u & 0x80000000u) ? ~u : (u | 0x80000000u);  // ascending-order bits
}

// ---- K1: per-(image,chunk) 13-bit histogram, written coalesced (no global atomics) ----
__global__ __launch_bounds__(256) void k_hist(const float* __restrict__ logits,
                                              u32* __restrict__ bhist) {
  __shared__ u32 h[NBIN];
  const int img = blockIdx.y, c = blockIdx.x;
  for (int i = threadIdx.x; i < NBIN; i += 256) h[i] = 0;
  __syncthreads();
  const float4* L = (const float4*)(logits + (size_t)img * NPI) + (size_t)c * F4PB;
  for (int i = threadIdx.x; i < F4PB; i += 256) {
    float4 v = L[i];
    atomicAdd(&h[fkey(v.x) >> 19], 1u);
    atomicAdd(&h[fkey(v.y) >> 19], 1u);
    atomicAdd(&h[fkey(v.z) >> 19], 1u);
    atomicAdd(&h[fkey(v.w) >> 19], 1u);
  }
  __syncthreads();
  // pack to u16 (per-block counts <= 30000) and store
  u32* O = bhist + (size_t)(img * CHUNK + c) * (NBIN / 2);
  for (int i = threadIdx.x; i < NBIN / 2; i += 256)
    O[i] = (h[2 * i] & 0xFFFFu) | (h[2 * i + 1] << 16);
}

// ---- K1b: reduce per-block hists -> per-image hist ----
__global__ void k_hreduce(const u16* __restrict__ bhist, u32* __restrict__ rhist) {
  int gid = blockIdx.x * 256 + threadIdx.x;       // 0 .. 8*8192-1
  int img = gid >> 13, bin = gid & (NBIN - 1);
  u32 s = 0;
#pragma unroll
  for (int c = 0; c < CHUNK; c++)
    s += bhist[(size_t)(img * CHUNK + c) * NBIN + bin];
  rhist[img * NBIN + bin] = s;
}

// ---- K2: find threshold bin (cumulative from top crosses PRE) ----
__global__ void k_select(const u32* __restrict__ hist, int* __restrict__ thresh) {
  const int img = blockIdx.x;
  const u32* H = hist + img * NBIN;
  __shared__ u32 part[256];
  u32 s = 0;
#pragma unroll
  for (int b = 0; b < 32; b++) s += H[threadIdx.x * 32 + b];
  part[threadIdx.x] = s;
  __syncthreads();
  if (threadIdx.x == 0) {
    u32 cum = 0;
    int pb = 255;
    for (; pb > 0; pb--) {
      if (cum + part[pb] >= (u32)PRE) break;
      cum += part[pb];
    }
    int bin;
    for (bin = pb * 32 + 31; bin >= pb * 32; bin--) {
      cum += H[bin];
      if (cum >= (u32)PRE) break;
    }
    if (bin < pb * 32) bin = pb * 32;  // safety clamp
    thresh[img] = bin;
  }
}

// ---- K3: compact candidates >= threshold bin; one global atomic per block ----
__global__ __launch_bounds__(256) void k_compact(const float* __restrict__ logits,
                                                 const int* __restrict__ thresh,
                                                 u32* __restrict__ cnt,
                                                 u64* __restrict__ cand) {
  __shared__ u64 buf[LBUF];
  __shared__ u32 bcnt;
  __shared__ u32 gbase;
  const int img = blockIdx.y, c = blockIdx.x;
  const int tb  = thresh[img];
  if (threadIdx.x == 0) bcnt = 0;
  __syncthreads();
  const float4* L = (const float4*)(logits + (size_t)img * NPI) + (size_t)c * F4PB;
  const int ebase = c * EPB;
  for (int i = threadIdx.x; i < F4PB; i += 256) {
    float4 v = L[i];
    float xs[4] = {v.x, v.y, v.z, v.w};
#pragma unroll
    for (int q = 0; q < 4; q++) {
      float x = xs[q];
      if ((int)(fkey(x) >> 19) >= tb) {
        // fp32 sigmoid with correctly-rounded exp: replicates numpy f32
        // tie structure exactly (verified: absmax 0.0)
        float ef = (float)exp(-(double)x);
        float sg = 1.0f / (1.0f + ef);
        u32 e = (u32)(ebase + 4 * i + q);
        u32 p = atomicAdd(&bcnt, 1u);
        if (p < LBUF)
          buf[p] = ((u64)fkey(sg) << 32) | (u64)(0xFFFFFFFFu - e);
      }
    }
  }
  __syncthreads();
  if (threadIdx.x == 0) {
    u32 m = bcnt < LBUF ? bcnt : LBUF;
    bcnt = m;
    gbase = atomicAdd(&cnt[img], m);
  }
  __syncthreads();
  const u32 m = bcnt, gb = gbase;
  for (u32 j = threadIdx.x; j < m; j += 256) {
    u32 pos = gb + j;
    if (pos < CAP) cand[img * CAP + pos] = buf[j];
  }
}

// ---- K4: exact rank (keys unique: idx embedded) + decode/clip, no sort ----
#define RB 8   // blocks per image; RB*256*2 = 4096 = CAP rows covered
__device__ __forceinline__ void emit_row(
    int img, int row, u64 key,
    const float* __restrict__ deltas, const float* __restrict__ anchors,
    float4* __restrict__ boxes, float* __restrict__ scores, u64* __restrict__ validw) {
  u32 hi  = (u32)(key >> 32);
  u32 idx = 0xFFFFFFFFu - (u32)(key & 0xFFFFFFFFu);
  u32 su  = (hi & 0x80000000u) ? (hi ^ 0x80000000u) : ~hi;
  float sc = __uint_as_float(su);
  size_t off = (size_t)img * NPI + idx;
  float4 d = ((const float4*)deltas)[off];
  float4 a = ((const float4*)anchors)[off];
  float aw = a.z - a.x, ah = a.w - a.y;
  float acx = a.x + 0.5f * aw, acy = a.y + 0.5f * ah;
  float cx = d.x * aw + acx, cy = d.y * ah + acy;
  float w = expf(d.z) * aw, h = expf(d.w) * ah;
  float x1 = cx - 0.5f * w, y1 = cy - 0.5f * h;
  float x2 = cx + 0.5f * w, y2 = cy + 0.5f * h;
  x1 = fminf(fmaxf(x1, 0.f), IMG_W);
  y1 = fminf(fmaxf(y1, 0.f), IMG_H);
  x2 = fminf(fmaxf(x2, 0.f), IMG_W);
  y2 = fminf(fmaxf(y2, 0.f), IMG_H);
  boxes[img * PRE + row]  = make_float4(x1, y1, x2, y2);
  scores[img * PRE + row] = sc;
  if (((x2 - x1) >= 1e-3f) && ((y2 - y1) >= 1e-3f))
    atomicOr(&validw[img * 16 + (row >> 6)], 1ull << (row & 63));
}

__global__ __launch_bounds__(256) void k_rank(
    const float* __restrict__ deltas, const float* __restrict__ anchors,
    const u32* __restrict__ cnt, const u64* __restrict__ cand,
    float4* __restrict__ boxes, float* __restrict__ scores, u64* __restrict__ validw) {
  __shared__ u64 skey[CAP];
  const int img = blockIdx.y;
  int n = (int)cnt[img];
  if (n > CAP) n = CAP;
  for (int i = threadIdx.x; i < n; i += 256) skey[i] = cand[img * CAP + i];
  __syncthreads();
  const int r0 = blockIdx.x * 256 + threadIdx.x;
  const int r1 = r0 + RB * 256;
  u64 k0 = (r0 < n) ? skey[r0] : 0ull;
  u64 k1 = (r1 < n) ? skey[r1] : 0ull;
  int c0 = 0, c1 = 0;
  for (int j = 0; j < n; j++) {
    u64 kj = skey[j];           // same address across lanes -> LDS broadcast
    c0 += (kj > k0);
    c1 += (kj > k1);
  }
  if (r0 < n && c0 < PRE) emit_row(img, c0, k0, deltas, anchors, boxes, scores, validw);
  if (r1 < n && c1 < PRE) emit_row(img, c1, k1, deltas, anchors, boxes, scores, validw);
}

// ---- K5: suppression bitmask, bit (i,c)=1 iff c>i && iou>thr ----
__global__ void k_iou(const float4* __restrict__ boxes, u64* __restrict__ mask) {
  __shared__ float4 sb[PRE];
  __shared__ float  sa[PRE];
  const int img = blockIdx.y;
  for (int c = threadIdx.x; c < PRE; c += 256) {
    float4 b = boxes[img * PRE + c];
    sb[c] = b;
    sa[c] = (b.z - b.x) * (b.w - b.y);
  }
  __syncthreads();
  for (int item = threadIdx.x; item < 1024; item += 256) {
    int r = item >> 4, w = item & 15;
    int i = blockIdx.x * 64 + r;
    if (i >= PRE) continue;
    float4 bi = sb[i];
    float  ai = sa[i];
    u64 bits = 0;
    int cbase  = w << 6;
    int kstart = (i + 1 > cbase) ? (i + 1 - cbase) : 0;
    int kend   = (PRE - cbase < 64) ? (PRE - cbase) : 64;
    for (int k = kstart; k < kend; k++) {
      int c = cbase + k;
      float4 bc = sb[c];
      float ltx = fmaxf(bi.x, bc.x), lty = fmaxf(bi.y, bc.y);
      float rbx = fminf(bi.z, bc.z), rby = fminf(bi.w, bc.w);
      float iw = fmaxf(rbx - ltx, 0.f), ih = fmaxf(rby - lty, 0.f);
      float inter = iw * ih;
      float iou = inter / (ai + sa[c] - inter + 1e-9f);
      if (iou > NMSF) bits |= (1ull << k);
    }
    mask[((size_t)img * PRE + i) * 16 + w] = bits;
  }
}

// ---- K6: greedy scan (1 wave/image, distributed bitmask) + output ----
#define LDSROWS 496
#define NMS_T   320
__global__ __launch_bounds__(NMS_T) void k_nms(
    const u64* __restrict__ mask, const u64* __restrict__ validw,
    const float4* __restrict__ boxes, const float* __restrict__ scores,
    float* __restrict__ out) {
  __shared__ u64 smask[LDSROWS * 16];
  __shared__ int skeeplist[POST];
  __shared__ int skept;
  const int img = blockIdx.x;
  const int tid = threadIdx.x;
  const u64* M = mask + (size_t)img * PRE * 16;
  for (int e = tid; e < LDSROWS * 16; e += NMS_T) smask[e] = M[e];
  __syncthreads();
  if (tid < 64) {
    u64 rem;
    if (tid < 16) {
      rem = ~validw[img * 16 + tid];
      if (tid == 15) rem |= 0xFFFFFF0000000000ull;  // rows 1000..1023 invalid
    } else {
      rem = ~0ull;
    }
    int i = 0, kept = 0;
    while (kept < POST) {
      u64 a = ~rem;
      int w = i >> 6;
      if (tid < w) a = 0;
      else if (tid == w) a &= (~0ull << (i & 63));
      u64 bal = __ballot(a != 0ull);
      if (bal == 0ull) break;
      int wsel = __builtin_ctzll(bal);
      int bitl = (a != 0ull) ? __builtin_ctzll(a) : 0;
      int bit  = __shfl(bitl, wsel);
      i = (wsel << 6) + bit;
      if (tid == 0) skeeplist[kept] = i;
      kept++;
      u64 roww = 0;
      if (tid < 16)
        roww = (i < LDSROWS) ? smask[i * 16 + tid] : M[(size_t)i * 16 + tid];
      rem |= roww;
      i++;
    }
    if (tid == 0) skept = kept;
  }
  __syncthreads();
  if (tid < POST) {
    float4 bx = make_float4(0.f, 0.f, 0.f, 0.f);
    float  sc = 0.f;
    if (tid < skept) {
      int i = skeeplist[tid];
      bx = boxes[img * PRE + i];
      sc = scores[img * PRE + i];
    }
    float* o = out + ((size_t)img * POST + tid) * 5;
    o[0] = bx.x; o[1] = bx.y; o[2] = bx.z; o[3] = bx.w; o[4] = sc;
  }
}

extern "C" void kernel_launch(void* const* d_in, const int* in_sizes, int n_in,
                              void* d_out, int out_size, void* d_ws, size_t ws_size,
                              hipStream_t stream) {
  const float* logits  = (const float*)d_in[0];
  const float* deltas  = (const float*)d_in[1];
  const float* anchors = (const float*)d_in[2];
  float* out = (float*)d_out;
  char* ws = (char*)d_ws;

  u32* cnt      = (u32*)(ws + CNT_OFF);
  u64* validw   = (u64*)(ws + VALID_OFF);
  int* thresh   = (int*)(ws + THRESH_OFF);
  u32* rhist    = (u32*)(ws + RHIST_OFF);
  u32* bhist    = (u32*)(ws + BHIST_OFF);
  u64* cand     = (u64*)(ws + CAND_OFF);
  float4* boxes = (float4*)(ws + BOX_OFF);
  float* scores = (float*)(ws + SCORE_OFF);
  u64* mask     = (u64*)(ws + MASK_OFF);

  hipMemsetAsync(ws, 0, ZERO_BYTES, stream);
  dim3 gh(CHUNK, B_IMG);
  k_hist<<<gh, 256, 0, stream>>>(logits, bhist);
  k_hreduce<<<(B_IMG * NBIN) / 256, 256, 0, stream>>>((const u16*)bhist, rhist);
  k_select<<<B_IMG, 256, 0, stream>>>(rhist, thresh);
  k_compact<<<gh, 256, 0, stream>>>(logits, thresh, cnt, cand);
  dim3 gr(RB, B_IMG);
  k_rank<<<gr, 256, 0, stream>>>(deltas, anchors, cnt, cand, boxes, scores, validw);
  dim3 g2(16, B_IMG);
  k_iou<<<g2, 256, 0, stream>>>(boxes, mask);
  k_nms<<<B_IMG, NMS_T, 0, stream>>>(mask, validw, boxes, scores, out);
}

// Round 4
// 245.123 us; speedup vs baseline: 1.5604x; 1.1823x over previous
//
#include <hip/hip_runtime.h>
#include <stdint.h>
#include <math.h>

typedef unsigned long long u64;
typedef unsigned int u32;
typedef unsigned short u16;

#define NPI   360000
#define B_IMG 8
#define PRE   1000
#define POST  300
#define CAP   4096
#define NMSF  0.7f
#define IMG_W 800.0f
#define IMG_H 800.0f

#define NBIN    4096          // 12-bit sortable-key histogram
#define KSHIFT  20            // fkey >> 20 -> 12-bit bin
#define CHUNK_H 24            // hist blocks per image
#define F4PB_H  (NPI / 4 / CHUNK_H)   // 3750
#define CHUNK_C 48            // compact blocks per image
#define F4PB_C  (NPI / 4 / CHUNK_C)   // 1875
#define EPB_C   (NPI / CHUNK_C)       // 7500
#define LBUF    1024          // per-block candidate buffer

// ---- workspace layout (bytes) ----
#define CNT_OFF    0          // 8*4
#define VALID_OFF  128        // 8*16*8 = 1024
#define THRESH_OFF 2048       // 8*4
#define RHIST_OFF  4096       // 8*4096*4 = 131072   -> 135168
#define BHIST_OFF  135168     // 8*24*4096*2 = 1572864 -> 1708032
#define CAND_OFF   1708032    // 8*4096*8 = 262144   -> 1970176
#define BOX_OFF    1970176    // 8*1000*16 = 128000  -> 2098176
#define SCORE_OFF  2098176    // 8*1000*4 = 32000    -> 2130176
#define MASK_OFF   2130176    // 8*1000*16*8 = 1024000 -> 3154176

__device__ __forceinline__ u32 fkey(float f) {
  u32 u = __float_as_uint(f);
  return (u & 0x80000000u) ? ~u : (u | 0x80000000u);  // ascending-order bits
}
__device__ __forceinline__ u64 rl64(u64 v, int lane) {
  u32 lo = (u32)__builtin_amdgcn_readlane((int)(u32)v, lane);
  u32 hi = (u32)__builtin_amdgcn_readlane((int)(u32)(v >> 32), lane);
  return ((u64)hi << 32) | lo;
}
__device__ __forceinline__ u64 sx64(u64 v, int m) {
  u32 lo = (u32)__shfl_xor((int)(u32)v, m, 64);
  u32 hi = (u32)__shfl_xor((int)(u32)(v >> 32), m, 64);
  return ((u64)hi << 32) | lo;
}

// ---- K1: per-(image,chunk) 12-bit histogram, no global atomics ----
__global__ __launch_bounds__(256) void k_hist(const float* __restrict__ logits,
                                              u32* __restrict__ bhist) {
  __shared__ u32 h[NBIN];
  const int img = blockIdx.y, c = blockIdx.x;
  for (int i = threadIdx.x; i < NBIN; i += 256) h[i] = 0;
  __syncthreads();
  const float4* L = (const float4*)(logits + (size_t)img * NPI) + (size_t)c * F4PB_H;
  for (int i = threadIdx.x; i < F4PB_H; i += 256) {
    float4 v = L[i];
    atomicAdd(&h[fkey(v.x) >> KSHIFT], 1u);
    atomicAdd(&h[fkey(v.y) >> KSHIFT], 1u);
    atomicAdd(&h[fkey(v.z) >> KSHIFT], 1u);
    atomicAdd(&h[fkey(v.w) >> KSHIFT], 1u);
  }
  __syncthreads();
  u32* O = bhist + (size_t)(img * CHUNK_H + c) * (NBIN / 2);
  for (int i = threadIdx.x; i < NBIN / 2; i += 256)
    O[i] = (h[2 * i] & 0xFFFFu) | (h[2 * i + 1] << 16);
}

// ---- K1b: reduce per-block hists -> per-image hist; zero cnt/validw ----
__global__ __launch_bounds__(256) void k_hreduce(const u32* __restrict__ bhist,
                                                 u32* __restrict__ rhist,
                                                 u32* __restrict__ cnt,
                                                 u64* __restrict__ validw) {
  int gid = blockIdx.x * 256 + threadIdx.x;   // 0 .. 8*2048-1 (u32 pairs)
  int img = gid >> 11, p = gid & 2047;
  u32 slo = 0, shi = 0;
#pragma unroll
  for (int c = 0; c < CHUNK_H; c++) {
    u32 v = bhist[(size_t)(img * CHUNK_H + c) * (NBIN / 2) + p];
    slo += v & 0xFFFFu;
    shi += v >> 16;
  }
  ((uint2*)rhist)[img * (NBIN / 2) + p] = make_uint2(slo, shi);
  if (blockIdx.x == 0) {
    if (threadIdx.x < 8) cnt[threadIdx.x] = 0;
    if (threadIdx.x < 128) validw[threadIdx.x] = 0ull;
  }
}

// ---- K2: find threshold bin (cumulative from top crosses PRE) ----
__global__ void k_select(const u32* __restrict__ hist, int* __restrict__ thresh) {
  const int img = blockIdx.x;
  const u32* H = hist + img * NBIN;
  __shared__ u32 part[256];
  u32 s = 0;
#pragma unroll
  for (int b = 0; b < 16; b++) s += H[threadIdx.x * 16 + b];
  part[threadIdx.x] = s;
  __syncthreads();
  if (threadIdx.x == 0) {
    u32 cum = 0;
    int pb = 255;
    for (; pb > 0; pb--) {
      if (cum + part[pb] >= (u32)PRE) break;
      cum += part[pb];
    }
    int bin;
    for (bin = pb * 16 + 15; bin >= pb * 16; bin--) {
      cum += H[bin];
      if (cum >= (u32)PRE) break;
    }
    if (bin < pb * 16) bin = pb * 16;  // safety clamp
    thresh[img] = bin;
  }
}

// ---- K3: compact candidates >= threshold bin; one global atomic per block ----
__global__ __launch_bounds__(256) void k_compact(const float* __restrict__ logits,
                                                 const int* __restrict__ thresh,
                                                 u32* __restrict__ cnt,
                                                 u64* __restrict__ cand) {
  __shared__ u64 buf[LBUF];
  __shared__ u32 bcnt;
  __shared__ u32 gbase;
  const int img = blockIdx.y, c = blockIdx.x;
  const int tb  = thresh[img];
  if (threadIdx.x == 0) bcnt = 0;
  __syncthreads();
  const float4* L = (const float4*)(logits + (size_t)img * NPI) + (size_t)c * F4PB_C;
  const int ebase = c * EPB_C;
  for (int i = threadIdx.x; i < F4PB_C; i += 256) {
    float4 v = L[i];
    float xs[4] = {v.x, v.y, v.z, v.w};
#pragma unroll
    for (int q = 0; q < 4; q++) {
      float x = xs[q];
      if ((int)(fkey(x) >> KSHIFT) >= tb) {
        // fp32 sigmoid with correctly-rounded exp: replicates numpy f32
        // tie structure exactly (verified: absmax 0.0)
        float ef = (float)exp(-(double)x);
        float sg = 1.0f / (1.0f + ef);
        u32 e = (u32)(ebase + 4 * i + q);
        u32 p = atomicAdd(&bcnt, 1u);
        if (p < LBUF)
          buf[p] = ((u64)fkey(sg) << 32) | (u64)(0xFFFFFFFFu - e);
      }
    }
  }
  __syncthreads();
  if (threadIdx.x == 0) {
    u32 m = bcnt < LBUF ? bcnt : LBUF;
    bcnt = m;
    gbase = atomicAdd(&cnt[img], m);
  }
  __syncthreads();
  const u32 m = bcnt, gb = gbase;
  for (u32 j = threadIdx.x; j < m; j += 256) {
    u32 pos = gb + j;
    if (pos < CAP) cand[img * CAP + pos] = buf[j];
  }
}

// ---- K4: exact rank (keys unique: idx embedded) + decode/clip, no sort ----
#define RB 8
__device__ __forceinline__ void emit_row(
    int img, int row, u64 key,
    const float* __restrict__ deltas, const float* __restrict__ anchors,
    float4* __restrict__ boxes, float* __restrict__ scores, u64* __restrict__ validw) {
  u32 hi  = (u32)(key >> 32);
  u32 idx = 0xFFFFFFFFu - (u32)(key & 0xFFFFFFFFu);
  u32 su  = (hi & 0x80000000u) ? (hi ^ 0x80000000u) : ~hi;
  float sc = __uint_as_float(su);
  size_t off = (size_t)img * NPI + idx;
  float4 d = ((const float4*)deltas)[off];
  float4 a = ((const float4*)anchors)[off];
  float aw = a.z - a.x, ah = a.w - a.y;
  float acx = a.x + 0.5f * aw, acy = a.y + 0.5f * ah;
  float cx = d.x * aw + acx, cy = d.y * ah + acy;
  float w = expf(d.z) * aw, h = expf(d.w) * ah;
  float x1 = cx - 0.5f * w, y1 = cy - 0.5f * h;
  float x2 = cx + 0.5f * w, y2 = cy + 0.5f * h;
  x1 = fminf(fmaxf(x1, 0.f), IMG_W);
  y1 = fminf(fmaxf(y1, 0.f), IMG_H);
  x2 = fminf(fmaxf(x2, 0.f), IMG_W);
  y2 = fminf(fmaxf(y2, 0.f), IMG_H);
  boxes[img * PRE + row]  = make_float4(x1, y1, x2, y2);
  scores[img * PRE + row] = sc;
  if (((x2 - x1) >= 1e-3f) && ((y2 - y1) >= 1e-3f))
    atomicOr(&validw[img * 16 + (row >> 6)], 1ull << (row & 63));
}

__global__ __launch_bounds__(256) void k_rank(
    const float* __restrict__ deltas, const float* __restrict__ anchors,
    const u32* __restrict__ cnt, const u64* __restrict__ cand,
    float4* __restrict__ boxes, float* __restrict__ scores, u64* __restrict__ validw) {
  __shared__ u64 skey[CAP];
  const int img = blockIdx.y;
  int n = (int)cnt[img];
  if (n > CAP) n = CAP;
  for (int i = threadIdx.x; i < n; i += 256) skey[i] = cand[img * CAP + i];
  __syncthreads();
  const int r0 = blockIdx.x * 256 + threadIdx.x;
  const int r1 = r0 + RB * 256;
  u64 k0 = (r0 < n) ? skey[r0] : 0ull;
  u64 k1 = (r1 < n) ? skey[r1] : 0ull;
  int c0 = 0, c1 = 0;
  for (int j = 0; j < n; j++) {
    u64 kj = skey[j];           // same address across lanes -> LDS broadcast
    c0 += (kj > k0);
    c1 += (kj > k1);
  }
  if (r0 < n && c0 < PRE) emit_row(img, c0, k0, deltas, anchors, boxes, scores, validw);
  if (r1 < n && c1 < PRE) emit_row(img, c1, k1, deltas, anchors, boxes, scores, validw);
}

// ---- K5: suppression bitmask, bit (i,c)=1 iff c>i && iou>thr ----
__global__ void k_iou(const float4* __restrict__ boxes, u64* __restrict__ mask) {
  __shared__ float4 sb[PRE];
  __shared__ float  sa[PRE];
  const int img = blockIdx.y;
  for (int c = threadIdx.x; c < PRE; c += 256) {
    float4 b = boxes[img * PRE + c];
    sb[c] = b;
    sa[c] = (b.z - b.x) * (b.w - b.y);
  }
  __syncthreads();
  for (int item = threadIdx.x; item < 1024; item += 256) {
    int r = item >> 4, w = item & 15;
    int i = blockIdx.x * 64 + r;
    if (i >= PRE) continue;
    float4 bi = sb[i];
    float  ai = sa[i];
    u64 bits = 0;
    int cbase  = w << 6;
    int kstart = (i + 1 > cbase) ? (i + 1 - cbase) : 0;
    int kend   = (PRE - cbase < 64) ? (PRE - cbase) : 64;
    for (int k = kstart; k < kend; k++) {
      int c = cbase + k;
      float4 bc = sb[c];
      float ltx = fmaxf(bi.x, bc.x), lty = fmaxf(bi.y, bc.y);
      float rbx = fminf(bi.z, bc.z), rby = fminf(bi.w, bc.w);
      float iw = fmaxf(rbx - ltx, 0.f), ih = fmaxf(rby - lty, 0.f);
      float inter = iw * ih;
      float iou = inter / (ai + sa[c] - inter + 1e-9f);
      if (iou > NMSF) bits |= (1ull << k);
    }
    mask[((size_t)img * PRE + i) * 16 + w] = bits;
  }
}

// ---- K6: chunked greedy scan — scalar in-chunk decisions via readlane ----
#define LDSROWS 496
#define NMS_T   320
__global__ __launch_bounds__(NMS_T) void k_nms(
    const u64* __restrict__ mask, const u64* __restrict__ validw,
    const float4* __restrict__ boxes, const float* __restrict__ scores,
    float* __restrict__ out) {
  __shared__ u64 smask[LDSROWS * 16];
  __shared__ int skeeplist[POST];
  __shared__ int skept;
  const int img = blockIdx.x;
  const int tid = threadIdx.x;
  const u64* M = mask + (size_t)img * PRE * 16;
  // wave0: diagonal 64x64 blocks -> registers (lane r holds row 64cc+r, word cc)
  u64 diag[16];
  if (tid < 64) {
#pragma unroll
    for (int cc = 0; cc < 16; cc++) {
      int row = cc * 64 + tid;
      diag[cc] = (row < PRE) ? M[(size_t)row * 16 + cc] : 0ull;
    }
  }
  for (int e = tid; e < LDSROWS * 16; e += NMS_T) smask[e] = M[e];
  __syncthreads();
  if (tid < 64) {
    const int lane = tid;
    const int w = lane & 15, g = lane >> 4;
    u64 rem = ~0ull;
    if (lane < 16) {
      rem = ~validw[img * 16 + lane];
      if (lane == 15) rem |= 0xFFFFFF0000000000ull;  // rows 1000..1023 invalid
    }
    int kept = 0;
#pragma unroll
    for (int cc = 0; cc < 16; cc++) {
      u64 alive = ~rl64(rem, cc);      // wave-uniform
      int kept0 = kept;
      while (alive != 0ull && kept < POST) {
        int r = __builtin_ctzll(alive);
        if (lane == 0) skeeplist[kept] = cc * 64 + r;
        kept++;
        u64 sup = rl64(diag[cc], r);   // row's in-chunk suppression word
        alive &= ~sup;
        alive &= ~(1ull << r);
      }
      int nc = kept - kept0;
      if (nc > 0 && kept < POST && cc < 15) {
        // batch-OR kept rows' full mask rows into rem (off the serial chain)
        u64 part = 0;
        for (int j = g; j < nc; j += 4) {
          int row = skeeplist[kept0 + j];
          part |= (row < LDSROWS) ? smask[row * 16 + w] : M[(size_t)row * 16 + w];
        }
        part |= sx64(part, 16);
        part |= sx64(part, 32);
        rem |= part;                   // only lanes <16 meaningful
      }
      if (kept >= POST) break;
    }
    if (lane == 0) skept = kept;
  }
  __syncthreads();
  if (tid < POST) {
    float4 bx = make_float4(0.f, 0.f, 0.f, 0.f);
    float  sc = 0.f;
    if (tid < skept) {
      int i = skeeplist[tid];
      bx = boxes[img * PRE + i];
      sc = scores[img * PRE + i];
    }
    float* o = out + ((size_t)img * POST + tid) * 5;
    o[0] = bx.x; o[1] = bx.y; o[2] = bx.z; o[3] = bx.w; o[4] = sc;
  }
}

extern "C" void kernel_launch(void* const* d_in, const int* in_sizes, int n_in,
                              void* d_out, int out_size, void* d_ws, size_t ws_size,
                              hipStream_t stream) {
  const float* logits  = (const float*)d_in[0];
  const float* deltas  = (const float*)d_in[1];
  const float* anchors = (const float*)d_in[2];
  float* out = (float*)d_out;
  char* ws = (char*)d_ws;

  u32* cnt      = (u32*)(ws + CNT_OFF);
  u64* validw   = (u64*)(ws + VALID_OFF);
  int* thresh   = (int*)(ws + THRESH_OFF);
  u32* rhist    = (u32*)(ws + RHIST_OFF);
  u32* bhist    = (u32*)(ws + BHIST_OFF);
  u64* cand     = (u64*)(ws + CAND_OFF);
  float4* boxes = (float4*)(ws + BOX_OFF);
  float* scores = (float*)(ws + SCORE_OFF);
  u64* mask     = (u64*)(ws + MASK_OFF);

  dim3 gh(CHUNK_H, B_IMG);
  k_hist<<<gh, 256, 0, stream>>>(logits, bhist);
  k_hreduce<<<(B_IMG * NBIN / 2) / 256, 256, 0, stream>>>(bhist, rhist, cnt, validw);
  k_select<<<B_IMG, 256, 0, stream>>>(rhist, thresh);
  dim3 gc(CHUNK_C, B_IMG);
  k_compact<<<gc, 256, 0, stream>>>(logits, thresh, cnt, cand);
  dim3 gr(RB, B_IMG);
  k_rank<<<gr, 256, 0, stream>>>(deltas, anchors, cnt, cand, boxes, scores, validw);
  dim3 g2(16, B_IMG);
  k_iou<<<g2, 256, 0, stream>>>(boxes, mask);
  k_nms<<<B_IMG, NMS_T, 0, stream>>>(mask, validw, boxes, scores, out);
}

// Round 5
// 214.164 us; speedup vs baseline: 1.7860x; 1.1446x over previous
//
#include <hip/hip_runtime.h>
#include <stdint.h>
#include <math.h>

typedef unsigned long long u64;
typedef unsigned int u32;
typedef unsigned short u16;

#define NPI   360000
#define B_IMG 8
#define PRE   1000
#define POST  300
#define CAP   4096
#define NMSF  0.7f
#define IMG_W 800.0f
#define IMG_H 800.0f

#define NBIN    4096          // 12-bit sortable-key histogram
#define KSHIFT  20            // fkey >> 20 -> 12-bit bin
#define CHUNK_H 24            // hist blocks per image
#define F4PB_H  (NPI / 4 / CHUNK_H)   // 3750
#define CHUNK_C 48            // compact blocks per image
#define F4PB_C  (NPI / 4 / CHUNK_C)   // 1875
#define EPB_C   (NPI / CHUNK_C)       // 7500
#define LBUF    1024          // per-block candidate buffer

// ---- workspace layout (bytes) ----
#define CNT_OFF    0          // 8*4
#define VALID_OFF  128        // 8*16*8 = 1024
#define THRESH_OFF 2048       // 8*4
#define RHIST_OFF  4096       // 8*4096*4 = 131072   -> 135168
#define BHIST_OFF  135168     // 8*24*4096*2 = 1572864 -> 1708032
#define CAND_OFF   1708032    // 8*4096*8 = 262144   -> 1970176
#define BOX_OFF    1970176    // 8*1000*16 = 128000  -> 2098176
#define SCORE_OFF  2098176    // 8*1000*4 = 32000    -> 2130176
#define MASK_OFF   2130176    // 8*1000*16*8 = 1024000 -> 3154176

__device__ __forceinline__ u32 fkey(float f) {
  u32 u = __float_as_uint(f);
  return (u & 0x80000000u) ? ~u : (u | 0x80000000u);  // ascending-order bits
}
__device__ __forceinline__ u64 rl64(u64 v, int lane) {
  u32 lo = (u32)__builtin_amdgcn_readlane((int)(u32)v, lane);
  u32 hi = (u32)__builtin_amdgcn_readlane((int)(u32)(v >> 32), lane);
  return ((u64)hi << 32) | lo;
}
__device__ __forceinline__ u64 sx64(u64 v, int m) {
  u32 lo = (u32)__shfl_xor((int)(u32)v, m, 64);
  u32 hi = (u32)__shfl_xor((int)(u32)(v >> 32), m, 64);
  return ((u64)hi << 32) | lo;
}

// ---- K1: per-(image,chunk) 12-bit histogram, no global atomics ----
__global__ __launch_bounds__(256) void k_hist(const float* __restrict__ logits,
                                              u32* __restrict__ bhist) {
  __shared__ u32 h[NBIN];
  const int img = blockIdx.y, c = blockIdx.x;
  for (int i = threadIdx.x; i < NBIN; i += 256) h[i] = 0;
  __syncthreads();
  const float4* L = (const float4*)(logits + (size_t)img * NPI) + (size_t)c * F4PB_H;
  for (int i = threadIdx.x; i < F4PB_H; i += 256) {
    float4 v = L[i];
    atomicAdd(&h[fkey(v.x) >> KSHIFT], 1u);
    atomicAdd(&h[fkey(v.y) >> KSHIFT], 1u);
    atomicAdd(&h[fkey(v.z) >> KSHIFT], 1u);
    atomicAdd(&h[fkey(v.w) >> KSHIFT], 1u);
  }
  __syncthreads();
  u32* O = bhist + (size_t)(img * CHUNK_H + c) * (NBIN / 2);
  for (int i = threadIdx.x; i < NBIN / 2; i += 256)
    O[i] = (h[2 * i] & 0xFFFFu) | (h[2 * i + 1] << 16);
}

// ---- K1b: reduce per-block hists -> per-image hist; zero cnt/validw ----
__global__ __launch_bounds__(256) void k_hreduce(const u32* __restrict__ bhist,
                                                 u32* __restrict__ rhist,
                                                 u32* __restrict__ cnt,
                                                 u64* __restrict__ validw) {
  int gid = blockIdx.x * 256 + threadIdx.x;   // 0 .. 8*2048-1 (u32 pairs)
  int img = gid >> 11, p = gid & 2047;
  u32 slo = 0, shi = 0;
#pragma unroll
  for (int c = 0; c < CHUNK_H; c++) {
    u32 v = bhist[(size_t)(img * CHUNK_H + c) * (NBIN / 2) + p];
    slo += v & 0xFFFFu;
    shi += v >> 16;
  }
  ((uint2*)rhist)[img * (NBIN / 2) + p] = make_uint2(slo, shi);
  if (blockIdx.x == 0) {
    if (threadIdx.x < 8) cnt[threadIdx.x] = 0;
    if (threadIdx.x < 128) validw[threadIdx.x] = 0ull;
  }
}

// ---- K2: find threshold bin (cumulative from top crosses PRE) ----
__global__ void k_select(const u32* __restrict__ hist, int* __restrict__ thresh) {
  const int img = blockIdx.x;
  const u32* H = hist + img * NBIN;
  __shared__ u32 part[256];
  u32 s = 0;
#pragma unroll
  for (int b = 0; b < 16; b++) s += H[threadIdx.x * 16 + b];
  part[threadIdx.x] = s;
  __syncthreads();
  if (threadIdx.x == 0) {
    u32 cum = 0;
    int pb = 255;
    for (; pb > 0; pb--) {
      if (cum + part[pb] >= (u32)PRE) break;
      cum += part[pb];
    }
    int bin;
    for (bin = pb * 16 + 15; bin >= pb * 16; bin--) {
      cum += H[bin];
      if (cum >= (u32)PRE) break;
    }
    if (bin < pb * 16) bin = pb * 16;  // safety clamp
    thresh[img] = bin;
  }
}

// ---- K3: compact candidates >= threshold bin; one global atomic per block ----
__global__ __launch_bounds__(256) void k_compact(const float* __restrict__ logits,
                                                 const int* __restrict__ thresh,
                                                 u32* __restrict__ cnt,
                                                 u64* __restrict__ cand) {
  __shared__ u64 buf[LBUF];
  __shared__ u32 bcnt;
  __shared__ u32 gbase;
  const int img = blockIdx.y, c = blockIdx.x;
  const int tb  = thresh[img];
  if (threadIdx.x == 0) bcnt = 0;
  __syncthreads();
  const float4* L = (const float4*)(logits + (size_t)img * NPI) + (size_t)c * F4PB_C;
  const int ebase = c * EPB_C;
  for (int i = threadIdx.x; i < F4PB_C; i += 256) {
    float4 v = L[i];
    float xs[4] = {v.x, v.y, v.z, v.w};
#pragma unroll
    for (int q = 0; q < 4; q++) {
      float x = xs[q];
      if ((int)(fkey(x) >> KSHIFT) >= tb) {
        // fp32 sigmoid with correctly-rounded exp: replicates numpy f32
        // tie structure exactly (verified: absmax 0.0)
        float ef = (float)exp(-(double)x);
        float sg = 1.0f / (1.0f + ef);
        u32 e = (u32)(ebase + 4 * i + q);
        u32 p = atomicAdd(&bcnt, 1u);
        if (p < LBUF)
          buf[p] = ((u64)fkey(sg) << 32) | (u64)(0xFFFFFFFFu - e);
      }
    }
  }
  __syncthreads();
  if (threadIdx.x == 0) {
    u32 m = bcnt < LBUF ? bcnt : LBUF;
    bcnt = m;
    gbase = atomicAdd(&cnt[img], m);
  }
  __syncthreads();
  const u32 m = bcnt, gb = gbase;
  for (u32 j = threadIdx.x; j < m; j += 256) {
    u32 pos = gb + j;
    if (pos < CAP) cand[img * CAP + pos] = buf[j];
  }
}

// ---- K4: exact rank (keys unique: idx embedded) + decode/clip, no sort ----
#define RB 8
__device__ __forceinline__ void emit_row(
    int img, int row, u64 key,
    const float* __restrict__ deltas, const float* __restrict__ anchors,
    float4* __restrict__ boxes, float* __restrict__ scores, u64* __restrict__ validw) {
  u32 hi  = (u32)(key >> 32);
  u32 idx = 0xFFFFFFFFu - (u32)(key & 0xFFFFFFFFu);
  u32 su  = (hi & 0x80000000u) ? (hi ^ 0x80000000u) : ~hi;
  float sc = __uint_as_float(su);
  size_t off = (size_t)img * NPI + idx;
  float4 d = ((const float4*)deltas)[off];
  float4 a = ((const float4*)anchors)[off];
  float aw = a.z - a.x, ah = a.w - a.y;
  float acx = a.x + 0.5f * aw, acy = a.y + 0.5f * ah;
  float cx = d.x * aw + acx, cy = d.y * ah + acy;
  float w = expf(d.z) * aw, h = expf(d.w) * ah;
  float x1 = cx - 0.5f * w, y1 = cy - 0.5f * h;
  float x2 = cx + 0.5f * w, y2 = cy + 0.5f * h;
  x1 = fminf(fmaxf(x1, 0.f), IMG_W);
  y1 = fminf(fmaxf(y1, 0.f), IMG_H);
  x2 = fminf(fmaxf(x2, 0.f), IMG_W);
  y2 = fminf(fmaxf(y2, 0.f), IMG_H);
  boxes[img * PRE + row]  = make_float4(x1, y1, x2, y2);
  scores[img * PRE + row] = sc;
  if (((x2 - x1) >= 1e-3f) && ((y2 - y1) >= 1e-3f))
    atomicOr(&validw[img * 16 + (row >> 6)], 1ull << (row & 63));
}

__global__ __launch_bounds__(256) void k_rank(
    const float* __restrict__ deltas, const float* __restrict__ anchors,
    const u32* __restrict__ cnt, const u64* __restrict__ cand,
    float4* __restrict__ boxes, float* __restrict__ scores, u64* __restrict__ validw) {
  __shared__ u64 skey[CAP];
  const int img = blockIdx.y;
  int n = (int)cnt[img];
  if (n > CAP) n = CAP;
  for (int i = threadIdx.x; i < n; i += 256) skey[i] = cand[img * CAP + i];
  __syncthreads();
  const int r0 = blockIdx.x * 256 + threadIdx.x;
  const int r1 = r0 + RB * 256;
  u64 k0 = (r0 < n) ? skey[r0] : 0ull;
  u64 k1 = (r1 < n) ? skey[r1] : 0ull;
  int c0 = 0, c1 = 0;
  for (int j = 0; j < n; j++) {
    u64 kj = skey[j];           // same address across lanes -> LDS broadcast
    c0 += (kj > k0);
    c1 += (kj > k1);
  }
  if (r0 < n && c0 < PRE) emit_row(img, c0, k0, deltas, anchors, boxes, scores, validw);
  if (r1 < n && c1 < PRE) emit_row(img, c1, k1, deltas, anchors, boxes, scores, validw);
}

// ---- K5: suppression bitmask via LDS broadcast (zero bank conflicts) ----
// grid (16, B): block = 1024 thr = 16 waves; wave wv computes mask word wv
// for the block's 64 rows (lane = row). Inner read sb[c] is same-address
// across all 64 lanes -> broadcast. bit (i,c)=1 iff c>i && iou>thr.
__global__ __launch_bounds__(1024) void k_iou(const float4* __restrict__ boxes,
                                              u64* __restrict__ mask) {
  __shared__ float4 sb[1024];
  __shared__ float  sa[1024];
  const int img = blockIdx.y;
  const int tid = threadIdx.x;
  {
    float4 b = (tid < PRE) ? boxes[img * PRE + tid]
                           : make_float4(0.f, 0.f, 0.f, 0.f);
    sb[tid] = b;
    sa[tid] = (b.z - b.x) * (b.w - b.y);
  }
  __syncthreads();
  const int lane = tid & 63;
  const int wv   = tid >> 6;          // word index 0..15
  const int i    = blockIdx.x * 64 + lane;   // row
  const bool rowok = (i < PRE);
  const float4 bi = sb[blockIdx.x * 64 + lane];  // garbage for i>=PRE, masked later
  const float  ai = sa[blockIdx.x * 64 + lane];
  const int cbase = wv << 6;
  u64 bits = 0;
#pragma unroll
  for (int k = 0; k < 64; k++) {
    int c = cbase + k;
    float4 bc = sb[c];                // broadcast read
    float ac  = sa[c];
    float ltx = fmaxf(bi.x, bc.x), lty = fmaxf(bi.y, bc.y);
    float rbx = fminf(bi.z, bc.z), rby = fminf(bi.w, bc.w);
    float iw = fmaxf(rbx - ltx, 0.f), ih = fmaxf(rby - lty, 0.f);
    float inter = iw * ih;
    float iou = inter / (ai + ac - inter + 1e-9f);  // IEEE div, matches ref
    bits |= (iou > NMSF) ? (1ull << k) : 0ull;
  }
  // keep only c > i
  int d = i - cbase;
  u64 gtmask = (d < 0) ? ~0ull : ((d >= 63) ? 0ull : (~0ull << (d + 1)));
  // keep only c < PRE
  int rem = PRE - cbase;
  u64 tmask = (rem >= 64) ? ~0ull : ((rem <= 0) ? 0ull : ((1ull << rem) - 1ull));
  bits &= gtmask & tmask;
  if (rowok) mask[((size_t)img * PRE + i) * 16 + wv] = bits;
}

// ---- K6: chunked greedy scan — scalar in-chunk decisions via readlane ----
#define LDSROWS 496
#define NMS_T   320
__global__ __launch_bounds__(NMS_T) void k_nms(
    const u64* __restrict__ mask, const u64* __restrict__ validw,
    const float4* __restrict__ boxes, const float* __restrict__ scores,
    float* __restrict__ out) {
  __shared__ u64 smask[LDSROWS * 16];
  __shared__ int skeeplist[POST];
  __shared__ int skept;
  const int img = blockIdx.x;
  const int tid = threadIdx.x;
  const u64* M = mask + (size_t)img * PRE * 16;
  // wave0: diagonal 64x64 blocks -> registers (lane r holds row 64cc+r, word cc)
  u64 diag[16];
  if (tid < 64) {
#pragma unroll
    for (int cc = 0; cc < 16; cc++) {
      int row = cc * 64 + tid;
      diag[cc] = (row < PRE) ? M[(size_t)row * 16 + cc] : 0ull;
    }
  }
  for (int e = tid; e < LDSROWS * 16; e += NMS_T) smask[e] = M[e];
  __syncthreads();
  if (tid < 64) {
    const int lane = tid;
    const int w = lane & 15, g = lane >> 4;
    u64 rem = ~0ull;
    if (lane < 16) {
      rem = ~validw[img * 16 + lane];
      if (lane == 15) rem |= 0xFFFFFF0000000000ull;  // rows 1000..1023 invalid
    }
    int kept = 0;
#pragma unroll
    for (int cc = 0; cc < 16; cc++) {
      u64 alive = ~rl64(rem, cc);      // wave-uniform
      int kept0 = kept;
      while (alive != 0ull && kept < POST) {
        int r = __builtin_ctzll(alive);
        if (lane == 0) skeeplist[kept] = cc * 64 + r;
        kept++;
        u64 sup = rl64(diag[cc], r);   // row's in-chunk suppression word
        alive &= ~sup;
        alive &= ~(1ull << r);
      }
      int nc = kept - kept0;
      if (nc > 0 && kept < POST && cc < 15) {
        // batch-OR kept rows' full mask rows into rem (off the serial chain)
        u64 part = 0;
        for (int j = g; j < nc; j += 4) {
          int row = skeeplist[kept0 + j];
          part |= (row < LDSROWS) ? smask[row * 16 + w] : M[(size_t)row * 16 + w];
        }
        part |= sx64(part, 16);
        part |= sx64(part, 32);
        rem |= part;                   // only lanes <16 meaningful
      }
      if (kept >= POST) break;
    }
    if (lane == 0) skept = kept;
  }
  __syncthreads();
  if (tid < POST) {
    float4 bx = make_float4(0.f, 0.f, 0.f, 0.f);
    float  sc = 0.f;
    if (tid < skept) {
      int i = skeeplist[tid];
      bx = boxes[img * PRE + i];
      sc = scores[img * PRE + i];
    }
    float* o = out + ((size_t)img * POST + tid) * 5;
    o[0] = bx.x; o[1] = bx.y; o[2] = bx.z; o[3] = bx.w; o[4] = sc;
  }
}

extern "C" void kernel_launch(void* const* d_in, const int* in_sizes, int n_in,
                              void* d_out, int out_size, void* d_ws, size_t ws_size,
                              hipStream_t stream) {
  const float* logits  = (const float*)d_in[0];
  const float* deltas  = (const float*)d_in[1];
  const float* anchors = (const float*)d_in[2];
  float* out = (float*)d_out;
  char* ws = (char*)d_ws;

  u32* cnt      = (u32*)(ws + CNT_OFF);
  u64* validw   = (u64*)(ws + VALID_OFF);
  int* thresh   = (int*)(ws + THRESH_OFF);
  u32* rhist    = (u32*)(ws + RHIST_OFF);
  u32* bhist    = (u32*)(ws + BHIST_OFF);
  u64* cand     = (u64*)(ws + CAND_OFF);
  float4* boxes = (float4*)(ws + BOX_OFF);
  float* scores = (float*)(ws + SCORE_OFF);
  u64* mask     = (u64*)(ws + MASK_OFF);

  dim3 gh(CHUNK_H, B_IMG);
  k_hist<<<gh, 256, 0, stream>>>(logits, bhist);
  k_hreduce<<<(B_IMG * NBIN / 2) / 256, 256, 0, stream>>>(bhist, rhist, cnt, validw);
  k_select<<<B_IMG, 256, 0, stream>>>(rhist, thresh);
  dim3 gc(CHUNK_C, B_IMG);
  k_compact<<<gc, 256, 0, stream>>>(logits, thresh, cnt, cand);
  dim3 gr(RB, B_IMG);
  k_rank<<<gr, 256, 0, stream>>>(deltas, anchors, cnt, cand, boxes, scores, validw);
  dim3 g2(16, B_IMG);
  k_iou<<<g2, 1024, 0, stream>>>(boxes, mask);
  k_nms<<<B_IMG, NMS_T, 0, stream>>>(mask, validw, boxes, scores, out);
}